// Round 3
// baseline (51.274 us; speedup 1.0000x reference)
//
#include <hip/hip_runtime.h>

// KAT group rational activation, elementwise:
//   out = p(z) / q(z)
//   p(z) = a0 + a1 z + ... + a5 z^5          (a shared across all groups)
//   q(z) = 1 + |b1| z + |b2| z^2 + |b3| z^3 + |b4| z^4   (b per group)
// Shapes: x (4, 4096, 2048) f32, G=8 groups of 256 channels.
// Memory-bound: 268 MB traffic -> 42.6 us floor at 6.3 TB/s measured ceiling.
// R0: 46.08 us (5.83 TB/s). R2: nontemporal hints (native vec type) + 2x unroll.

#define GROUPS  8

// __builtin_nontemporal_* requires a native clang vector type, not the
// HIP_vector_type<float,4> struct.
typedef float f32x4 __attribute__((ext_vector_type(4)));

__global__ __launch_bounds__(256) void kat_rational_kernel(
    const f32x4* __restrict__ x4,
    const float* __restrict__ wn,   // 6 numerator coeffs (shared)
    const float* __restrict__ wd,   // 8*4 denominator coeffs
    f32x4*       __restrict__ out4,
    int n4)
{
    const int tid    = blockIdx.x * blockDim.x + threadIdx.x;
    const int stride = gridDim.x * blockDim.x;

    // Element index of this thread's accesses are tid*4 + k*stride*4.
    // stride*4 = 2,097,152 elements, a multiple of D=2048 (guaranteed by
    // kernel_launch's grid choice), so the group index g = (d/256) is
    // loop-invariant per thread: g = (tid >> 6) & 7.
    const int g = (tid >> 6) & (GROUPS - 1);

    const float a0 = wn[0], a1 = wn[1], a2 = wn[2];
    const float a3 = wn[3], a4 = wn[4], a5 = wn[5];
    const float c1 = fabsf(wd[g * 4 + 0]);
    const float c2 = fabsf(wd[g * 4 + 1]);
    const float c3 = fabsf(wd[g * 4 + 2]);
    const float c4 = fabsf(wd[g * 4 + 3]);

    // 2x unroll: two independent float4 loads in flight per iteration.
    for (int i = tid; i < n4; i += 2 * stride) {
        const int i1 = i + stride;
        f32x4 v0 = __builtin_nontemporal_load(&x4[i]);
        f32x4 v1 = {};
        const bool has1 = (i1 < n4);
        if (has1) v1 = __builtin_nontemporal_load(&x4[i1]);

        f32x4 r0, r1;
#pragma unroll
        for (int j = 0; j < 4; ++j) {
            const float z = v0[j];
            float p = fmaf(a5, z, a4);
            p = fmaf(p, z, a3);
            p = fmaf(p, z, a2);
            p = fmaf(p, z, a1);
            p = fmaf(p, z, a0);
            float q = fmaf(c4, z, c3);
            q = fmaf(q, z, c2);
            q = fmaf(q, z, c1);
            q = fmaf(q, z, 1.0f);
            r0[j] = p / q;   // IEEE f32 division for accuracy
        }
#pragma unroll
        for (int j = 0; j < 4; ++j) {
            const float z = v1[j];
            float p = fmaf(a5, z, a4);
            p = fmaf(p, z, a3);
            p = fmaf(p, z, a2);
            p = fmaf(p, z, a1);
            p = fmaf(p, z, a0);
            float q = fmaf(c4, z, c3);
            q = fmaf(q, z, c2);
            q = fmaf(q, z, c1);
            q = fmaf(q, z, 1.0f);
            r1[j] = p / q;
        }

        __builtin_nontemporal_store(r0, &out4[i]);
        if (has1) __builtin_nontemporal_store(r1, &out4[i1]);
    }
}

extern "C" void kernel_launch(void* const* d_in, const int* in_sizes, int n_in,
                              void* d_out, int out_size, void* d_ws, size_t ws_size,
                              hipStream_t stream) {
    const float* x  = (const float*)d_in[0];
    const float* wn = (const float*)d_in[1];  // (1,6) numerator
    const float* wd = (const float*)d_in[2];  // (8,4) denominator
    float* out = (float*)d_out;

    const int n  = in_sizes[0];       // 33,554,432
    const int n4 = n / 4;             // 8,388,608 float4s

    // 2048 blocks x 256 threads = 8 blocks/CU on 256 CUs, 32 waves/CU.
    // stride*4 elements = 2,097,152 = multiple of D=2048 -> group index
    // loop-invariant per thread (required by the kernel's hoisting).
    const int block = 256;
    const int grid  = 2048;
    kat_rational_kernel<<<grid, block, 0, stream>>>(
        (const f32x4*)x, wn, wd, (f32x4*)out, n4);
}

// Round 4
// 46.377 us; speedup vs baseline: 1.1056x; 1.1056x over previous
//
#include <hip/hip_runtime.h>

// KAT group rational activation, elementwise:
//   out = p(z) / q(z)
//   p(z) = a0 + a1 z + ... + a5 z^5          (a shared across all groups)
//   q(z) = 1 + |b1| z + |b2| z^2 + |b3| z^3 + |b4| z^4   (b per group)
// Shapes: x (4, 4096, 2048) f32, G=8 groups of 256 channels.
// Memory-bound: 268 MB traffic -> 42.6 us floor at 6.3 TB/s measured ceiling.
// R0: 46.08 us (no unroll, no nt). R2: 51.27 us (2x unroll + nontemporal)
// -- REGRESSED. R3: isolate -- keep 2x unroll, drop ALL nontemporal hints.

#define GROUPS  8

typedef float f32x4 __attribute__((ext_vector_type(4)));

__global__ __launch_bounds__(256) void kat_rational_kernel(
    const f32x4* __restrict__ x4,
    const float* __restrict__ wn,   // 6 numerator coeffs (shared)
    const float* __restrict__ wd,   // 8*4 denominator coeffs
    f32x4*       __restrict__ out4,
    int n4)
{
    const int tid    = blockIdx.x * blockDim.x + threadIdx.x;
    const int stride = gridDim.x * blockDim.x;

    // Element index of this thread's accesses are tid*4 + k*stride*4.
    // stride*4 = 2,097,152 elements, a multiple of D=2048 (guaranteed by
    // kernel_launch's grid choice), so the group index g = (d/256) is
    // loop-invariant per thread: g = (tid >> 6) & 7.
    const int g = (tid >> 6) & (GROUPS - 1);

    const float a0 = wn[0], a1 = wn[1], a2 = wn[2];
    const float a3 = wn[3], a4 = wn[4], a5 = wn[5];
    const float c1 = fabsf(wd[g * 4 + 0]);
    const float c2 = fabsf(wd[g * 4 + 1]);
    const float c3 = fabsf(wd[g * 4 + 2]);
    const float c4 = fabsf(wd[g * 4 + 3]);

    // 2x unroll: two independent float4 loads in flight per iteration.
    for (int i = tid; i < n4; i += 2 * stride) {
        const int i1 = i + stride;
        f32x4 v0 = x4[i];
        f32x4 v1 = {};
        const bool has1 = (i1 < n4);
        if (has1) v1 = x4[i1];

        f32x4 r0, r1;
#pragma unroll
        for (int j = 0; j < 4; ++j) {
            const float z = v0[j];
            float p = fmaf(a5, z, a4);
            p = fmaf(p, z, a3);
            p = fmaf(p, z, a2);
            p = fmaf(p, z, a1);
            p = fmaf(p, z, a0);
            float q = fmaf(c4, z, c3);
            q = fmaf(q, z, c2);
            q = fmaf(q, z, c1);
            q = fmaf(q, z, 1.0f);
            r0[j] = p / q;   // IEEE f32 division for accuracy
        }
#pragma unroll
        for (int j = 0; j < 4; ++j) {
            const float z = v1[j];
            float p = fmaf(a5, z, a4);
            p = fmaf(p, z, a3);
            p = fmaf(p, z, a2);
            p = fmaf(p, z, a1);
            p = fmaf(p, z, a0);
            float q = fmaf(c4, z, c3);
            q = fmaf(q, z, c2);
            q = fmaf(q, z, c1);
            q = fmaf(q, z, 1.0f);
            r1[j] = p / q;
        }

        out4[i] = r0;
        if (has1) out4[i1] = r1;
    }
}

extern "C" void kernel_launch(void* const* d_in, const int* in_sizes, int n_in,
                              void* d_out, int out_size, void* d_ws, size_t ws_size,
                              hipStream_t stream) {
    const float* x  = (const float*)d_in[0];
    const float* wn = (const float*)d_in[1];  // (1,6) numerator
    const float* wd = (const float*)d_in[2];  // (8,4) denominator
    float* out = (float*)d_out;

    const int n  = in_sizes[0];       // 33,554,432
    const int n4 = n / 4;             // 8,388,608 float4s

    // 2048 blocks x 256 threads = 8 blocks/CU on 256 CUs, 32 waves/CU.
    // stride*4 elements = 2,097,152 = multiple of D=2048 -> group index
    // loop-invariant per thread (required by the kernel's hoisting).
    const int block = 256;
    const int grid  = 2048;
    kat_rational_kernel<<<grid, block, 0, stream>>>(
        (const f32x4*)x, wn, wd, (f32x4*)out, n4);
}